// Round 1
// baseline (4709.491 us; speedup 1.0000x reference)
//
#include <hip/hip_runtime.h>
#include <hip/hip_bf16.h>

#define N_NODES 50000
#define N_EDGES 625000
#define IN_DIM  300
#define HID     128
#define NLAYERS 4
#define NB      8   // nodes per block in GEMM-ish kernels

// ---------------- degree ----------------
__global__ void k_deg(const int* __restrict__ dst, float* __restrict__ deg) {
    int stride = gridDim.x * blockDim.x;
    for (int e = blockIdx.x * blockDim.x + threadIdx.x; e < N_EDGES; e += stride)
        atomicAdd(&deg[dst[e]], 1.0f);
}

__global__ void k_invdeg(float* deg) {
    int i = blockIdx.x * blockDim.x + threadIdx.x;
    if (i < N_NODES) deg[i] = 1.0f / fmaxf(deg[i], 1.0f);
}

// ---------------- embedding: h = relu(x @ W + b) ----------------
__global__ void k_embed(const float* __restrict__ x, const float* __restrict__ W,
                        const float* __restrict__ b, float* __restrict__ h) {
    __shared__ float xs[NB][IN_DIM];   // 8*300*4 = 9.6 KB
    const int n0 = blockIdx.x * NB;
    const int f  = threadIdx.x;        // 0..127

    for (int idx = f; idx < NB * IN_DIM; idx += HID) {
        int i = idx / IN_DIM, k = idx - i * IN_DIM;
        xs[i][k] = x[(size_t)(n0 + i) * IN_DIM + k];
    }
    __syncthreads();

    float acc[NB];
    const float bias = b[f];
#pragma unroll
    for (int i = 0; i < NB; i++) acc[i] = bias;

    for (int k4 = 0; k4 < IN_DIM; k4 += 4) {
        float w0 = W[(size_t)(k4 + 0) * HID + f];
        float w1 = W[(size_t)(k4 + 1) * HID + f];
        float w2 = W[(size_t)(k4 + 2) * HID + f];
        float w3 = W[(size_t)(k4 + 3) * HID + f];
#pragma unroll
        for (int i = 0; i < NB; i++) {
            float4 a = *reinterpret_cast<const float4*>(&xs[i][k4]);
            acc[i] += a.x * w0 + a.y * w1 + a.z * w2 + a.w * w3;
        }
    }
#pragma unroll
    for (int i = 0; i < NB; i++)
        h[(size_t)(n0 + i) * HID + f] = fmaxf(acc[i], 0.0f);
}

// ---------------- scatter: agg[dst] += h[src] ----------------
__global__ void k_scatter(const int* __restrict__ src, const int* __restrict__ dst,
                          const float* __restrict__ h, float* agg) {
    const long long total  = (long long)N_EDGES * 32;   // 32 float4-chunks per edge
    const long long stride = (long long)gridDim.x * blockDim.x;
    for (long long t = (long long)blockIdx.x * blockDim.x + threadIdx.x; t < total; t += stride) {
        int e = (int)(t >> 5);
        int c = ((int)t & 31) * 4;
        int s = src[e], d = dst[e];
        float4 v = *reinterpret_cast<const float4*>(&h[(size_t)s * HID + c]);
        float* o = &agg[(size_t)d * HID + c];
        atomicAdd(o + 0, v.x);
        atomicAdd(o + 1, v.y);
        atomicAdd(o + 2, v.z);
        atomicAdd(o + 3, v.w);
    }
}

// ---------------- combine: h_out = relu((agg*inv_deg) @ Wl + bl + h_in @ Wr) ----------------
// NOTE: h_out may alias agg (rows staged through LDS before overwrite).
__global__ void k_combine(const float* __restrict__ h_in, const float* agg,
                          const float* __restrict__ inv_deg,
                          const float* __restrict__ Wl, const float* __restrict__ bl,
                          const float* __restrict__ Wr, float* h_out) {
    __shared__ float a_s[NB][HID];
    __shared__ float h_s[NB][HID];
    const int n0 = blockIdx.x * NB;
    const int f  = threadIdx.x;   // 0..127

#pragma unroll
    for (int i = 0; i < NB; i++) {
        float id = inv_deg[n0 + i];
        a_s[i][f] = agg[(size_t)(n0 + i) * HID + f] * id;
        h_s[i][f] = h_in[(size_t)(n0 + i) * HID + f];
    }
    __syncthreads();

    float acc[NB];
    const float bias = bl[f];
#pragma unroll
    for (int i = 0; i < NB; i++) acc[i] = bias;

    for (int k4 = 0; k4 < HID; k4 += 4) {
        float wl0 = Wl[(size_t)(k4 + 0) * HID + f];
        float wl1 = Wl[(size_t)(k4 + 1) * HID + f];
        float wl2 = Wl[(size_t)(k4 + 2) * HID + f];
        float wl3 = Wl[(size_t)(k4 + 3) * HID + f];
        float wr0 = Wr[(size_t)(k4 + 0) * HID + f];
        float wr1 = Wr[(size_t)(k4 + 1) * HID + f];
        float wr2 = Wr[(size_t)(k4 + 2) * HID + f];
        float wr3 = Wr[(size_t)(k4 + 3) * HID + f];
#pragma unroll
        for (int i = 0; i < NB; i++) {
            float4 a = *reinterpret_cast<const float4*>(&a_s[i][k4]);
            float4 v = *reinterpret_cast<const float4*>(&h_s[i][k4]);
            acc[i] += a.x * wl0 + a.y * wl1 + a.z * wl2 + a.w * wl3
                    + v.x * wr0 + v.y * wr1 + v.z * wr2 + v.w * wr3;
        }
    }
#pragma unroll
    for (int i = 0; i < NB; i++)
        h_out[(size_t)(n0 + i) * HID + f] = fmaxf(acc[i], 0.0f);
}

extern "C" void kernel_launch(void* const* d_in, const int* in_sizes, int n_in,
                              void* d_out, int out_size, void* d_ws, size_t ws_size,
                              hipStream_t stream) {
    const float* x     = (const float*)d_in[0];
    const int*   ei    = (const int*)d_in[1];
    const float* emb_W = (const float*)d_in[2];
    const float* emb_b = (const float*)d_in[3];
    const float* Wl    = (const float*)d_in[4];
    const float* bl    = (const float*)d_in[5];
    const float* Wr    = (const float*)d_in[6];
    float* out = (float*)d_out;

    const int* src = ei;
    const int* dst = ei + N_EDGES;

    char* ws   = (char*)d_ws;
    float* deg = (float*)ws;                                        // N floats
    size_t off = (((size_t)N_NODES * sizeof(float)) + 255) & ~(size_t)255;
    float* hB  = (float*)(ws + off);                                // N*HID floats

    // degree -> inv_deg (in place)
    hipMemsetAsync(deg, 0, N_NODES * sizeof(float), stream);
    k_deg<<<1024, 256, 0, stream>>>(dst, deg);
    k_invdeg<<<(N_NODES + 255) / 256, 256, 0, stream>>>(deg);

    // h0 = relu(x @ emb_W + emb_b)  -> d_out (bufA)
    k_embed<<<N_NODES / NB, HID, 0, stream>>>(x, emb_W, emb_b, out);

    float* bufA = out;
    float* bufB = hB;
    for (int l = 0; l < NLAYERS; l++) {
        float* h_in = (l & 1) ? bufB : bufA;
        float* aggb = (l & 1) ? bufA : bufB;   // agg buffer doubles as h_out
        hipMemsetAsync(aggb, 0, (size_t)N_NODES * HID * sizeof(float), stream);
        k_scatter<<<4096, 256, 0, stream>>>(src, dst, h_in, aggb);
        k_combine<<<N_NODES / NB, HID, 0, stream>>>(h_in, aggb, deg,
                                                    Wl + (size_t)l * HID * HID,
                                                    bl + (size_t)l * HID,
                                                    Wr + (size_t)l * HID * HID,
                                                    aggb);
    }
    // l=3 wrote into bufA == d_out
}

// Round 2
// 850.426 us; speedup vs baseline: 5.5378x; 5.5378x over previous
//
#include <hip/hip_runtime.h>
#include <hip/hip_bf16.h>

#define N_NODES 50000
#define N_EDGES 625000
#define IN_DIM  300
#define HID     128
#define NLAYERS 4
#define NB      8   // nodes per block in GEMM-ish kernels

// ---------------- degree histogram (int) ----------------
__global__ void k_deg(const int* __restrict__ dst, int* __restrict__ deg) {
    int stride = gridDim.x * blockDim.x;
    for (int e = blockIdx.x * blockDim.x + threadIdx.x; e < N_EDGES; e += stride)
        atomicAdd(&deg[dst[e]], 1);
}

// ---------------- exclusive scan of deg -> rowcur (single block) ----------------
#define SCAN_T 256
__global__ void k_scan(const int* __restrict__ deg, int* __restrict__ rowcur) {
    __shared__ int sums[SCAN_T];
    const int C = (N_NODES + SCAN_T - 1) / SCAN_T;   // 196
    const int t = threadIdx.x;
    const int b = t * C;
    const int e = min(b + C, N_NODES);
    int s = 0;
    for (int i = b; i < e; i++) s += deg[i];
    sums[t] = s;
    __syncthreads();
    // Hillis-Steele inclusive scan
    for (int off = 1; off < SCAN_T; off <<= 1) {
        int v = sums[t];
        int u = (t >= off) ? sums[t - off] : 0;
        __syncthreads();
        sums[t] = v + u;
        __syncthreads();
    }
    int excl = (t == 0) ? 0 : sums[t - 1];
    for (int i = b; i < e; i++) { rowcur[i] = excl; excl += deg[i]; }
}

// ---------------- deg(int) -> 1/max(deg,1) (float, in place) ----------------
__global__ void k_invdeg(int* degbuf) {
    int i = blockIdx.x * blockDim.x + threadIdx.x;
    if (i < N_NODES) {
        int d = degbuf[i];
        float inv = 1.0f / (float)max(d, 1);
        ((float*)degbuf)[i] = inv;
    }
}

// ---------------- CSR fill: csr_src[pos] = src[e]; rowcur becomes row-end ----------------
__global__ void k_fill(const int* __restrict__ src, const int* __restrict__ dst,
                       int* __restrict__ rowcur, int* __restrict__ csr_src) {
    int stride = gridDim.x * blockDim.x;
    for (int e = blockIdx.x * blockDim.x + threadIdx.x; e < N_EDGES; e += stride) {
        int d = dst[e];
        int pos = atomicAdd(&rowcur[d], 1);
        csr_src[pos] = src[e];
    }
}

// ---------------- embedding: h = relu(x @ W + b) ----------------
__global__ void k_embed(const float* __restrict__ x, const float* __restrict__ W,
                        const float* __restrict__ b, float* __restrict__ h) {
    __shared__ float xs[NB][IN_DIM];   // 8*300*4 = 9.6 KB
    const int n0 = blockIdx.x * NB;
    const int f  = threadIdx.x;        // 0..127

    for (int idx = f; idx < NB * IN_DIM; idx += HID) {
        int i = idx / IN_DIM, k = idx - i * IN_DIM;
        xs[i][k] = x[(size_t)(n0 + i) * IN_DIM + k];
    }
    __syncthreads();

    float acc[NB];
    const float bias = b[f];
#pragma unroll
    for (int i = 0; i < NB; i++) acc[i] = bias;

    for (int k4 = 0; k4 < IN_DIM; k4 += 4) {
        float w0 = W[(size_t)(k4 + 0) * HID + f];
        float w1 = W[(size_t)(k4 + 1) * HID + f];
        float w2 = W[(size_t)(k4 + 2) * HID + f];
        float w3 = W[(size_t)(k4 + 3) * HID + f];
#pragma unroll
        for (int i = 0; i < NB; i++) {
            float4 a = *reinterpret_cast<const float4*>(&xs[i][k4]);
            acc[i] += a.x * w0 + a.y * w1 + a.z * w2 + a.w * w3;
        }
    }
#pragma unroll
    for (int i = 0; i < NB; i++)
        h[(size_t)(n0 + i) * HID + f] = fmaxf(acc[i], 0.0f);
}

// ---------------- gather-aggregate: agg[n] = (sum_{e in row n} h[csr_src[e]]) * invdeg[n] ----
// one 64-lane wave per node; lane owns a float2 of the feature row
__global__ void k_gather(const int* __restrict__ rowend, const int* __restrict__ csr_src,
                         const float* __restrict__ h, const float* __restrict__ invdeg,
                         float* __restrict__ agg) {
    const int node = blockIdx.x * (blockDim.x >> 6) + (threadIdx.x >> 6);
    if (node >= N_NODES) return;
    const int lane = threadIdx.x & 63;
    const int beg = (node == 0) ? 0 : rowend[node - 1];
    const int end = rowend[node];

    float2 acc = make_float2(0.0f, 0.0f);
    for (int e = beg; e < end; e++) {
        int s = csr_src[e];
        float2 v = *reinterpret_cast<const float2*>(&h[(size_t)s * HID + lane * 2]);
        acc.x += v.x;
        acc.y += v.y;
    }
    const float id = invdeg[node];
    float2 o = make_float2(acc.x * id, acc.y * id);
    *reinterpret_cast<float2*>(&agg[(size_t)node * HID + lane * 2]) = o;
}

// ---------------- combine: h_out = relu(agg @ Wl + bl + h_in @ Wr) ----------------
// NOTE: h_out may alias agg (rows staged through LDS before overwrite).
__global__ void k_combine(const float* __restrict__ h_in, const float* agg,
                          const float* __restrict__ Wl, const float* __restrict__ bl,
                          const float* __restrict__ Wr, float* h_out) {
    __shared__ float a_s[NB][HID];
    __shared__ float h_s[NB][HID];
    const int n0 = blockIdx.x * NB;
    const int f  = threadIdx.x;   // 0..127

#pragma unroll
    for (int i = 0; i < NB; i++) {
        a_s[i][f] = agg[(size_t)(n0 + i) * HID + f];
        h_s[i][f] = h_in[(size_t)(n0 + i) * HID + f];
    }
    __syncthreads();

    float acc[NB];
    const float bias = bl[f];
#pragma unroll
    for (int i = 0; i < NB; i++) acc[i] = bias;

    for (int k4 = 0; k4 < HID; k4 += 4) {
        float wl0 = Wl[(size_t)(k4 + 0) * HID + f];
        float wl1 = Wl[(size_t)(k4 + 1) * HID + f];
        float wl2 = Wl[(size_t)(k4 + 2) * HID + f];
        float wl3 = Wl[(size_t)(k4 + 3) * HID + f];
        float wr0 = Wr[(size_t)(k4 + 0) * HID + f];
        float wr1 = Wr[(size_t)(k4 + 1) * HID + f];
        float wr2 = Wr[(size_t)(k4 + 2) * HID + f];
        float wr3 = Wr[(size_t)(k4 + 3) * HID + f];
#pragma unroll
        for (int i = 0; i < NB; i++) {
            float4 a = *reinterpret_cast<const float4*>(&a_s[i][k4]);
            float4 v = *reinterpret_cast<const float4*>(&h_s[i][k4]);
            acc[i] += a.x * wl0 + a.y * wl1 + a.z * wl2 + a.w * wl3
                    + v.x * wr0 + v.y * wr1 + v.z * wr2 + v.w * wr3;
        }
    }
#pragma unroll
    for (int i = 0; i < NB; i++)
        h_out[(size_t)(n0 + i) * HID + f] = fmaxf(acc[i], 0.0f);
}

extern "C" void kernel_launch(void* const* d_in, const int* in_sizes, int n_in,
                              void* d_out, int out_size, void* d_ws, size_t ws_size,
                              hipStream_t stream) {
    const float* x     = (const float*)d_in[0];
    const int*   ei    = (const int*)d_in[1];
    const float* emb_W = (const float*)d_in[2];
    const float* emb_b = (const float*)d_in[3];
    const float* Wl    = (const float*)d_in[4];
    const float* bl    = (const float*)d_in[5];
    const float* Wr    = (const float*)d_in[6];
    float* out = (float*)d_out;

    const int* src = ei;
    const int* dst = ei + N_EDGES;

    // workspace layout
    char* ws = (char*)d_ws;
    size_t o = 0;
    int* degbuf = (int*)(ws + o); o += ((size_t)N_NODES * 4 + 255) & ~(size_t)255;      // int deg -> float invdeg
    int* rowcur = (int*)(ws + o); o += ((size_t)N_NODES * 4 + 255) & ~(size_t)255;      // scan -> row ends
    int* csrsrc = (int*)(ws + o); o += ((size_t)N_EDGES * 4 + 255) & ~(size_t)255;      // CSR src indices
    float* hB   = (float*)(ws + o);                                                     // N*HID floats

    // ---- build CSR (per call; deterministic work) ----
    hipMemsetAsync(degbuf, 0, (size_t)N_NODES * sizeof(int), stream);
    k_deg<<<1024, 256, 0, stream>>>(dst, degbuf);
    k_scan<<<1, SCAN_T, 0, stream>>>(degbuf, rowcur);
    k_invdeg<<<(N_NODES + 255) / 256, 256, 0, stream>>>(degbuf);
    const float* invdeg = (const float*)degbuf;
    k_fill<<<1024, 256, 0, stream>>>(src, dst, rowcur, csrsrc);
    // rowcur[n] is now the END offset of row n

    // ---- h0 = relu(x @ emb_W + emb_b) -> d_out (bufA) ----
    k_embed<<<N_NODES / NB, HID, 0, stream>>>(x, emb_W, emb_b, out);

    float* bufA = out;
    float* bufB = hB;
    for (int l = 0; l < NLAYERS; l++) {
        float* h_in = (l & 1) ? bufB : bufA;
        float* aggb = (l & 1) ? bufA : bufB;   // agg buffer doubles as h_out
        k_gather<<<(N_NODES + 3) / 4, 256, 0, stream>>>(rowcur, csrsrc, h_in, invdeg, aggb);
        k_combine<<<N_NODES / NB, HID, 0, stream>>>(h_in, aggb,
                                                    Wl + (size_t)l * HID * HID,
                                                    bl + (size_t)l * HID,
                                                    Wr + (size_t)l * HID * HID,
                                                    aggb);
    }
    // l=3 wrote into bufA == d_out
}

// Round 3
// 670.428 us; speedup vs baseline: 7.0246x; 1.2685x over previous
//
#include <hip/hip_runtime.h>
#include <hip/hip_bf16.h>

#define N_NODES 50000
#define N_EDGES 625000
#define IN_DIM  300
#define HID     128
#define NLAYERS 4
#define NB      8   // nodes per block in embed

typedef __hip_bfloat16 bf16;
typedef __attribute__((ext_vector_type(8))) short short8;   // 8 bf16 = 4 VGPRs
typedef __attribute__((ext_vector_type(4))) float f32x4;

// ---------------- degree histogram (int) ----------------
__global__ void k_deg(const int* __restrict__ dst, int* __restrict__ deg) {
    int stride = gridDim.x * blockDim.x;
    for (int e = blockIdx.x * blockDim.x + threadIdx.x; e < N_EDGES; e += stride)
        atomicAdd(&deg[dst[e]], 1);
}

// ---------------- exclusive scan of deg -> rowcur (single block) ----------------
#define SCAN_T 256
__global__ void k_scan(const int* __restrict__ deg, int* __restrict__ rowcur) {
    __shared__ int sums[SCAN_T];
    const int C = (N_NODES + SCAN_T - 1) / SCAN_T;
    const int t = threadIdx.x;
    const int b = t * C;
    const int e = min(b + C, N_NODES);
    int s = 0;
    for (int i = b; i < e; i++) s += deg[i];
    sums[t] = s;
    __syncthreads();
    for (int off = 1; off < SCAN_T; off <<= 1) {
        int v = sums[t];
        int u = (t >= off) ? sums[t - off] : 0;
        __syncthreads();
        sums[t] = v + u;
        __syncthreads();
    }
    int excl = (t == 0) ? 0 : sums[t - 1];
    for (int i = b; i < e; i++) { rowcur[i] = excl; excl += deg[i]; }
}

// ---------------- deg(int) -> 1/max(deg,1) (float, in place) ----------------
__global__ void k_invdeg(int* degbuf) {
    int i = blockIdx.x * blockDim.x + threadIdx.x;
    if (i < N_NODES) {
        int d = degbuf[i];
        float inv = 1.0f / (float)max(d, 1);
        ((float*)degbuf)[i] = inv;
    }
}

// ---------------- CSR fill ----------------
__global__ void k_fill(const int* __restrict__ src, const int* __restrict__ dst,
                       int* __restrict__ rowcur, int* __restrict__ csr_src) {
    int stride = gridDim.x * blockDim.x;
    for (int e = blockIdx.x * blockDim.x + threadIdx.x; e < N_EDGES; e += stride) {
        int d = dst[e];
        int pos = atomicAdd(&rowcur[d], 1);
        csr_src[pos] = src[e];
    }
}

// ---------------- W -> W^T bf16 conversion ----------------
__global__ void k_wconv(const float* __restrict__ Wl, const float* __restrict__ Wr,
                        bf16* __restrict__ WlT, bf16* __restrict__ WrT) {
    int idx = blockIdx.x * 256 + threadIdx.x;
    if (idx >= NLAYERS * HID * HID) return;
    int l = idx / (HID * HID);
    int rem = idx - l * HID * HID;
    int k = rem >> 7;
    int f = rem & 127;
    size_t o = (size_t)l * HID * HID + (size_t)f * HID + k;
    WlT[o] = __float2bfloat16(Wl[idx]);
    WrT[o] = __float2bfloat16(Wr[idx]);
}

// ---------------- embedding: h = relu(x @ W + b), bf16 out ----------------
__global__ void k_embed(const float* __restrict__ x, const float* __restrict__ W,
                        const float* __restrict__ b, bf16* __restrict__ h) {
    __shared__ float xs[NB][IN_DIM];
    const int n0 = blockIdx.x * NB;
    const int f  = threadIdx.x;

    for (int idx = f; idx < NB * IN_DIM; idx += HID) {
        int i = idx / IN_DIM, k = idx - i * IN_DIM;
        xs[i][k] = x[(size_t)(n0 + i) * IN_DIM + k];
    }
    __syncthreads();

    float acc[NB];
    const float bias = b[f];
#pragma unroll
    for (int i = 0; i < NB; i++) acc[i] = bias;

    for (int k4 = 0; k4 < IN_DIM; k4 += 4) {
        float w0 = W[(size_t)(k4 + 0) * HID + f];
        float w1 = W[(size_t)(k4 + 1) * HID + f];
        float w2 = W[(size_t)(k4 + 2) * HID + f];
        float w3 = W[(size_t)(k4 + 3) * HID + f];
#pragma unroll
        for (int i = 0; i < NB; i++) {
            float4 a = *reinterpret_cast<const float4*>(&xs[i][k4]);
            acc[i] += a.x * w0 + a.y * w1 + a.z * w2 + a.w * w3;
        }
    }
#pragma unroll
    for (int i = 0; i < NB; i++)
        h[(size_t)(n0 + i) * HID + f] = __float2bfloat16(fmaxf(acc[i], 0.0f));
}

// ---------------- gather-aggregate (bf16 h, bf16 agg out) ----------------
// one 64-lane wave per node; lane owns 2 features (4 B)
__global__ void k_gather(const int* __restrict__ rowend, const int* __restrict__ csr_src,
                         const bf16* __restrict__ h, const float* __restrict__ invdeg,
                         bf16* __restrict__ agg) {
    const int node = blockIdx.x * (blockDim.x >> 6) + (threadIdx.x >> 6);
    if (node >= N_NODES) return;
    const int lane = threadIdx.x & 63;
    const int beg = (node == 0) ? 0 : rowend[node - 1];
    const int end = rowend[node];

    float ax = 0.0f, ay = 0.0f;
    for (int e = beg; e < end; e++) {
        int s = csr_src[e];
        unsigned int v = *reinterpret_cast<const unsigned int*>(h + (size_t)s * HID + lane * 2);
        ax += __uint_as_float((v & 0xffffu) << 16);
        ay += __uint_as_float(v & 0xffff0000u);
    }
    const float id = invdeg[node];
    bf16* o = agg + (size_t)node * HID + lane * 2;
    o[0] = __float2bfloat16(ax * id);
    o[1] = __float2bfloat16(ay * id);
}

// ---------------- combine via MFMA: out = relu(agg @ Wl + bl + h_in @ Wr) ----------------
// A-frag: lane holds A[r0 + (lane&15)][k0 + (lane>>4)*8 + j], j=0..7 (16B contiguous)
// B-frag: lane holds B[k0 + (lane>>4)*8 + j][c0 + (lane&15)] = WT[c0+(lane&15)][k0+...]
// C/D  : col = lane&15, row = (lane>>4)*4 + reg   [verified layout]
template<int STORE_F32>
__global__ void k_combine_mfma(const bf16* __restrict__ agg, const bf16* __restrict__ h_in,
                               const bf16* __restrict__ WlT, const bf16* __restrict__ WrT,
                               const float* __restrict__ bl, void* __restrict__ outp) {
    const int wid  = threadIdx.x >> 6;          // 0..3
    const int lane = threadIdx.x & 63;
    const int r0   = blockIdx.x * 64 + wid * 16;
    const int lrow = lane & 15;
    const int kgrp = lane >> 4;

    f32x4 acc[8];
#pragma unroll
    for (int c = 0; c < 8; c++) acc[c] = (f32x4){0.f, 0.f, 0.f, 0.f};

    const int arow = min(r0 + lrow, N_NODES - 1);

#pragma unroll
    for (int m = 0; m < 2; m++) {
        const bf16* A  = m ? h_in : agg;
        const bf16* BT = m ? WrT  : WlT;
#pragma unroll
        for (int kk = 0; kk < 4; kk++) {
            const int k0 = kk * 32 + kgrp * 8;
            short8 a = *reinterpret_cast<const short8*>(A + (size_t)arow * HID + k0);
#pragma unroll
            for (int c = 0; c < 8; c++) {
                short8 b = *reinterpret_cast<const short8*>(BT + (size_t)(c * 16 + lrow) * HID + k0);
                acc[c] = __builtin_amdgcn_mfma_f32_16x16x32_bf16(a, b, acc[c], 0, 0, 0);
            }
        }
    }

#pragma unroll
    for (int c = 0; c < 8; c++) {
        const int col = c * 16 + lrow;
        const float bias = bl[col];
#pragma unroll
        for (int r = 0; r < 4; r++) {
            const int row = r0 + kgrp * 4 + r;
            if (row < N_NODES) {
                float v = fmaxf(acc[c][r] + bias, 0.0f);
                if (STORE_F32)
                    ((float*)outp)[(size_t)row * HID + col] = v;
                else
                    ((bf16*)outp)[(size_t)row * HID + col] = __float2bfloat16(v);
            }
        }
    }
}

extern "C" void kernel_launch(void* const* d_in, const int* in_sizes, int n_in,
                              void* d_out, int out_size, void* d_ws, size_t ws_size,
                              hipStream_t stream) {
    const float* x     = (const float*)d_in[0];
    const int*   ei    = (const int*)d_in[1];
    const float* emb_W = (const float*)d_in[2];
    const float* emb_b = (const float*)d_in[3];
    const float* Wl    = (const float*)d_in[4];
    const float* bl    = (const float*)d_in[5];
    const float* Wr    = (const float*)d_in[6];

    const int* src = ei;
    const int* dst = ei + N_EDGES;

    // workspace layout
    char* ws = (char*)d_ws;
    size_t o = 0;
    int*  degbuf = (int*)(ws + o);  o += ((size_t)N_NODES * 4 + 255) & ~(size_t)255;
    int*  rowcur = (int*)(ws + o);  o += ((size_t)N_NODES * 4 + 255) & ~(size_t)255;
    int*  csrsrc = (int*)(ws + o);  o += ((size_t)N_EDGES * 4 + 255) & ~(size_t)255;
    bf16* WlT    = (bf16*)(ws + o); o += ((size_t)NLAYERS * HID * HID * 2 + 255) & ~(size_t)255;
    bf16* WrT    = (bf16*)(ws + o); o += ((size_t)NLAYERS * HID * HID * 2 + 255) & ~(size_t)255;
    bf16* bufA   = (bf16*)(ws + o); o += ((size_t)N_NODES * HID * 2 + 255) & ~(size_t)255;
    bf16* bufB   = (bf16*)(ws + o);

    // ---- build CSR ----
    hipMemsetAsync(degbuf, 0, (size_t)N_NODES * sizeof(int), stream);
    k_deg<<<1024, 256, 0, stream>>>(dst, degbuf);
    k_scan<<<1, SCAN_T, 0, stream>>>(degbuf, rowcur);
    k_invdeg<<<(N_NODES + 255) / 256, 256, 0, stream>>>(degbuf);
    const float* invdeg = (const float*)degbuf;
    k_fill<<<1024, 256, 0, stream>>>(src, dst, rowcur, csrsrc);

    // ---- W^T bf16 ----
    k_wconv<<<(NLAYERS * HID * HID + 255) / 256, 256, 0, stream>>>(Wl, Wr, WlT, WrT);

    // ---- h0 = relu(x @ emb_W + emb_b) -> bufA (bf16) ----
    k_embed<<<N_NODES / NB, HID, 0, stream>>>(x, emb_W, emb_b, bufA);

    const int cgrid = (N_NODES + 63) / 64;   // 782
    for (int l = 0; l < NLAYERS; l++) {
        bf16* h_in = (l & 1) ? bufB : bufA;
        bf16* aggb = (l & 1) ? bufA : bufB;
        k_gather<<<(N_NODES + 3) / 4, 256, 0, stream>>>(rowcur, csrsrc, h_in, invdeg, aggb);
        const bf16* wlt = WlT + (size_t)l * HID * HID;
        const bf16* wrt = WrT + (size_t)l * HID * HID;
        const float* blp = bl + (size_t)l * HID;
        if (l == NLAYERS - 1)
            k_combine_mfma<1><<<cgrid, 256, 0, stream>>>(aggb, h_in, wlt, wrt, blp, d_out);
        else
            k_combine_mfma<0><<<cgrid, 256, 0, stream>>>(aggb, h_in, wlt, wrt, blp, aggb);
    }
}

// Round 4
// 485.480 us; speedup vs baseline: 9.7007x; 1.3810x over previous
//
#include <hip/hip_runtime.h>
#include <hip/hip_bf16.h>

#define N_NODES 50000
#define N_EDGES 625000
#define IN_DIM  300
#define KPAD    320   // IN_DIM padded to multiple of 32
#define HID     128
#define NLAYERS 4

typedef __hip_bfloat16 bf16;
typedef __attribute__((ext_vector_type(8))) short short8;   // 8 bf16 = 4 VGPRs
typedef __attribute__((ext_vector_type(4))) float f32x4;

__device__ inline short f2bf(float v) {
    bf16 t = __float2bfloat16(v);
    return *reinterpret_cast<short*>(&t);
}

// ---------------- degree histogram (int) ----------------
__global__ void k_deg(const int* __restrict__ dst, int* __restrict__ deg) {
    int stride = gridDim.x * blockDim.x;
    for (int e = blockIdx.x * blockDim.x + threadIdx.x; e < N_EDGES; e += stride)
        atomicAdd(&deg[dst[e]], 1);
}

// ---------------- exclusive scan of deg -> rowcur (single block, 1024 thr) ----------------
#define SCAN_T 1024
__global__ void k_scan(const int* __restrict__ deg, int* __restrict__ rowcur) {
    __shared__ int sums[SCAN_T];
    const int C = (N_NODES + SCAN_T - 1) / SCAN_T;   // 49
    const int t = threadIdx.x;
    const int b = t * C;
    const int e = min(b + C, N_NODES);
    int s = 0;
    for (int i = b; i < e; i++) s += deg[i];
    sums[t] = s;
    __syncthreads();
    for (int off = 1; off < SCAN_T; off <<= 1) {
        int v = sums[t];
        int u = (t >= off) ? sums[t - off] : 0;
        __syncthreads();
        sums[t] = v + u;
        __syncthreads();
    }
    int excl = (t == 0) ? 0 : sums[t - 1];
    for (int i = b; i < e; i++) { rowcur[i] = excl; excl += deg[i]; }
}

// ---------------- deg(int) -> 1/max(deg,1) (float, in place) ----------------
__global__ void k_invdeg(int* degbuf) {
    int i = blockIdx.x * blockDim.x + threadIdx.x;
    if (i < N_NODES) {
        int d = degbuf[i];
        float inv = 1.0f / (float)max(d, 1);
        ((float*)degbuf)[i] = inv;
    }
}

// ---------------- CSR fill ----------------
__global__ void k_fill(const int* __restrict__ src, const int* __restrict__ dst,
                       int* __restrict__ rowcur, int* __restrict__ csr_src) {
    int stride = gridDim.x * blockDim.x;
    for (int e = blockIdx.x * blockDim.x + threadIdx.x; e < N_EDGES; e += stride) {
        int d = dst[e];
        int pos = atomicAdd(&rowcur[d], 1);
        csr_src[pos] = src[e];
    }
}

// ---------------- Wl/Wr -> W^T bf16 ----------------
__global__ void k_wconv(const float* __restrict__ Wl, const float* __restrict__ Wr,
                        bf16* __restrict__ WlT, bf16* __restrict__ WrT) {
    int idx = blockIdx.x * 256 + threadIdx.x;
    if (idx >= NLAYERS * HID * HID) return;
    int l = idx / (HID * HID);
    int rem = idx - l * HID * HID;
    int k = rem >> 7;
    int f = rem & 127;
    size_t o = (size_t)l * HID * HID + (size_t)f * HID + k;
    WlT[o] = __float2bfloat16(Wl[idx]);
    WrT[o] = __float2bfloat16(Wr[idx]);
}

// ---------------- emb_W[300][128] -> embT[128][KPAD] bf16 (zero-padded K) ----------------
__global__ void k_wembT(const float* __restrict__ W, bf16* __restrict__ embT) {
    int idx = blockIdx.x * 256 + threadIdx.x;
    if (idx >= HID * KPAD) return;
    int f = idx / KPAD, k = idx - f * KPAD;
    float v = (k < IN_DIM) ? W[(size_t)k * HID + f] : 0.0f;
    embT[idx] = __float2bfloat16(v);
}

// ---------------- embedding via MFMA: h = relu(x @ W + b), bf16 out ----------------
// A: x rows f32 -> bf16 in-register; B: embT (K-major per output col)
__global__ void k_embed_mfma(const float* __restrict__ x, const bf16* __restrict__ embT,
                             const float* __restrict__ b, bf16* __restrict__ h) {
    const int wid  = threadIdx.x >> 6;
    const int lane = threadIdx.x & 63;
    const int r0   = blockIdx.x * 64 + wid * 16;
    const int lrow = lane & 15;
    const int kgrp = lane >> 4;

    const int arow = min(r0 + lrow, N_NODES - 1);
    const float* xrow = x + (size_t)arow * IN_DIM;

    f32x4 acc[8];
#pragma unroll
    for (int c = 0; c < 8; c++) acc[c] = (f32x4){0.f, 0.f, 0.f, 0.f};

    for (int kk = 0; kk < KPAD / 32; kk++) {
        const int k0 = kk * 32 + kgrp * 8;
        short8 a;
        if (kk < 9) {   // k0+8 <= 296 <= 300 for kgrp<=3 when kk<9? (kk=8: k0 max 280, ok)
            float4 f0 = *reinterpret_cast<const float4*>(xrow + k0);
            float4 f1 = *reinterpret_cast<const float4*>(xrow + k0 + 4);
            a[0] = f2bf(f0.x); a[1] = f2bf(f0.y); a[2] = f2bf(f0.z); a[3] = f2bf(f0.w);
            a[4] = f2bf(f1.x); a[5] = f2bf(f1.y); a[6] = f2bf(f1.z); a[7] = f2bf(f1.w);
        } else {        // tail: k in [288,320), valid < 300
#pragma unroll
            for (int j = 0; j < 8; j++) {
                int k = k0 + j;
                a[j] = f2bf((k < IN_DIM) ? xrow[k] : 0.0f);
            }
        }
#pragma unroll
        for (int c = 0; c < 8; c++) {
            short8 bfrag = *reinterpret_cast<const short8*>(embT + (size_t)(c * 16 + lrow) * KPAD + k0);
            acc[c] = __builtin_amdgcn_mfma_f32_16x16x32_bf16(a, bfrag, acc[c], 0, 0, 0);
        }
    }

#pragma unroll
    for (int c = 0; c < 8; c++) {
        const int col = c * 16 + lrow;
        const float bias = b[col];
#pragma unroll
        for (int r = 0; r < 4; r++) {
            const int row = r0 + kgrp * 4 + r;
            if (row < N_NODES)
                h[(size_t)row * HID + col] = __float2bfloat16(fmaxf(acc[c][r] + bias, 0.0f));
        }
    }
}

// ---------------- gather-aggregate (bf16 h, bf16 agg out), 4-way edge unroll ----------------
__global__ void k_gather(const int* __restrict__ rowend, const int* __restrict__ csr_src,
                         const bf16* __restrict__ h, const float* __restrict__ invdeg,
                         bf16* __restrict__ agg) {
    const int node = blockIdx.x * (blockDim.x >> 6) + (threadIdx.x >> 6);
    if (node >= N_NODES) return;
    const int lane = threadIdx.x & 63;
    const int beg = (node == 0) ? 0 : rowend[node - 1];
    const int end = rowend[node];

    float ax0 = 0.f, ay0 = 0.f, ax1 = 0.f, ay1 = 0.f;
    float ax2 = 0.f, ay2 = 0.f, ax3 = 0.f, ay3 = 0.f;
    int e = beg;
    for (; e + 4 <= end; e += 4) {
        int s0 = csr_src[e + 0];
        int s1 = csr_src[e + 1];
        int s2 = csr_src[e + 2];
        int s3 = csr_src[e + 3];
        unsigned v0 = *reinterpret_cast<const unsigned*>(h + (size_t)s0 * HID + lane * 2);
        unsigned v1 = *reinterpret_cast<const unsigned*>(h + (size_t)s1 * HID + lane * 2);
        unsigned v2 = *reinterpret_cast<const unsigned*>(h + (size_t)s2 * HID + lane * 2);
        unsigned v3 = *reinterpret_cast<const unsigned*>(h + (size_t)s3 * HID + lane * 2);
        ax0 += __uint_as_float((v0 & 0xffffu) << 16); ay0 += __uint_as_float(v0 & 0xffff0000u);
        ax1 += __uint_as_float((v1 & 0xffffu) << 16); ay1 += __uint_as_float(v1 & 0xffff0000u);
        ax2 += __uint_as_float((v2 & 0xffffu) << 16); ay2 += __uint_as_float(v2 & 0xffff0000u);
        ax3 += __uint_as_float((v3 & 0xffffu) << 16); ay3 += __uint_as_float(v3 & 0xffff0000u);
    }
    for (; e < end; e++) {
        int s = csr_src[e];
        unsigned v = *reinterpret_cast<const unsigned*>(h + (size_t)s * HID + lane * 2);
        ax0 += __uint_as_float((v & 0xffffu) << 16);
        ay0 += __uint_as_float(v & 0xffff0000u);
    }
    const float id = invdeg[node];
    float ax = (ax0 + ax1) + (ax2 + ax3);
    float ay = (ay0 + ay1) + (ay2 + ay3);
    bf16* o = agg + (size_t)node * HID + lane * 2;
    o[0] = __float2bfloat16(ax * id);
    o[1] = __float2bfloat16(ay * id);
}

// ---------------- combine via MFMA: out = relu(agg @ Wl + bl + h_in @ Wr) ----------------
template<int STORE_F32>
__global__ void k_combine_mfma(const bf16* __restrict__ agg, const bf16* __restrict__ h_in,
                               const bf16* __restrict__ WlT, const bf16* __restrict__ WrT,
                               const float* __restrict__ bl, void* __restrict__ outp) {
    const int wid  = threadIdx.x >> 6;
    const int lane = threadIdx.x & 63;
    const int r0   = blockIdx.x * 64 + wid * 16;
    const int lrow = lane & 15;
    const int kgrp = lane >> 4;

    f32x4 acc[8];
#pragma unroll
    for (int c = 0; c < 8; c++) acc[c] = (f32x4){0.f, 0.f, 0.f, 0.f};

    const int arow = min(r0 + lrow, N_NODES - 1);

#pragma unroll
    for (int m = 0; m < 2; m++) {
        const bf16* A  = m ? h_in : agg;
        const bf16* BT = m ? WrT  : WlT;
#pragma unroll
        for (int kk = 0; kk < 4; kk++) {
            const int k0 = kk * 32 + kgrp * 8;
            short8 a = *reinterpret_cast<const short8*>(A + (size_t)arow * HID + k0);
#pragma unroll
            for (int c = 0; c < 8; c++) {
                short8 b = *reinterpret_cast<const short8*>(BT + (size_t)(c * 16 + lrow) * HID + k0);
                acc[c] = __builtin_amdgcn_mfma_f32_16x16x32_bf16(a, b, acc[c], 0, 0, 0);
            }
        }
    }

#pragma unroll
    for (int c = 0; c < 8; c++) {
        const int col = c * 16 + lrow;
        const float bias = bl[col];
#pragma unroll
        for (int r = 0; r < 4; r++) {
            const int row = r0 + kgrp * 4 + r;
            if (row < N_NODES) {
                float v = fmaxf(acc[c][r] + bias, 0.0f);
                if (STORE_F32)
                    ((float*)outp)[(size_t)row * HID + col] = v;
                else
                    ((bf16*)outp)[(size_t)row * HID + col] = __float2bfloat16(v);
            }
        }
    }
}

extern "C" void kernel_launch(void* const* d_in, const int* in_sizes, int n_in,
                              void* d_out, int out_size, void* d_ws, size_t ws_size,
                              hipStream_t stream) {
    const float* x     = (const float*)d_in[0];
    const int*   ei    = (const int*)d_in[1];
    const float* emb_W = (const float*)d_in[2];
    const float* emb_b = (const float*)d_in[3];
    const float* Wl    = (const float*)d_in[4];
    const float* bl    = (const float*)d_in[5];
    const float* Wr    = (const float*)d_in[6];

    const int* src = ei;
    const int* dst = ei + N_EDGES;

    // workspace layout
    char* ws = (char*)d_ws;
    size_t o = 0;
    int*  degbuf = (int*)(ws + o);  o += ((size_t)N_NODES * 4 + 255) & ~(size_t)255;
    int*  rowcur = (int*)(ws + o);  o += ((size_t)N_NODES * 4 + 255) & ~(size_t)255;
    int*  csrsrc = (int*)(ws + o);  o += ((size_t)N_EDGES * 4 + 255) & ~(size_t)255;
    bf16* WlT    = (bf16*)(ws + o); o += ((size_t)NLAYERS * HID * HID * 2 + 255) & ~(size_t)255;
    bf16* WrT    = (bf16*)(ws + o); o += ((size_t)NLAYERS * HID * HID * 2 + 255) & ~(size_t)255;
    bf16* embT   = (bf16*)(ws + o); o += ((size_t)HID * KPAD * 2 + 255) & ~(size_t)255;
    bf16* bufA   = (bf16*)(ws + o); o += ((size_t)N_NODES * HID * 2 + 255) & ~(size_t)255;
    bf16* bufB   = (bf16*)(ws + o);

    // ---- build CSR ----
    hipMemsetAsync(degbuf, 0, (size_t)N_NODES * sizeof(int), stream);
    k_deg<<<1024, 256, 0, stream>>>(dst, degbuf);
    k_scan<<<1, SCAN_T, 0, stream>>>(degbuf, rowcur);
    k_invdeg<<<(N_NODES + 255) / 256, 256, 0, stream>>>(degbuf);
    const float* invdeg = (const float*)degbuf;
    k_fill<<<1024, 256, 0, stream>>>(src, dst, rowcur, csrsrc);

    // ---- weight prep ----
    k_wconv<<<(NLAYERS * HID * HID + 255) / 256, 256, 0, stream>>>(Wl, Wr, WlT, WrT);
    k_wembT<<<(HID * KPAD + 255) / 256, 256, 0, stream>>>(emb_W, embT);

    // ---- h0 = relu(x @ emb_W + emb_b) -> bufA (bf16), via MFMA ----
    const int cgrid = (N_NODES + 63) / 64;   // 782
    k_embed_mfma<<<cgrid, 256, 0, stream>>>(x, embT, emb_b, bufA);

    for (int l = 0; l < NLAYERS; l++) {
        bf16* h_in = (l & 1) ? bufB : bufA;
        bf16* aggb = (l & 1) ? bufA : bufB;
        k_gather<<<(N_NODES + 3) / 4, 256, 0, stream>>>(rowcur, csrsrc, h_in, invdeg, aggb);
        const bf16* wlt = WlT + (size_t)l * HID * HID;
        const bf16* wrt = WrT + (size_t)l * HID * HID;
        const float* blp = bl + (size_t)l * HID;
        if (l == NLAYERS - 1)
            k_combine_mfma<1><<<cgrid, 256, 0, stream>>>(aggb, h_in, wlt, wrt, blp, d_out);
        else
            k_combine_mfma<0><<<cgrid, 256, 0, stream>>>(aggb, h_in, wlt, wrt, blp, aggb);
    }
}

// Round 5
// 424.591 us; speedup vs baseline: 11.0918x; 1.1434x over previous
//
#include <hip/hip_runtime.h>
#include <hip/hip_bf16.h>

#define N_NODES 50000
#define N_EDGES 625000
#define IN_DIM  300
#define KPAD    320   // IN_DIM padded to multiple of 32
#define HID     128
#define NLAYERS 4

#define SB      256                            // scan block size
#define NCH     ((N_NODES + SB - 1) / SB)      // 196 chunks

typedef __hip_bfloat16 bf16;
typedef __attribute__((ext_vector_type(8))) short short8;   // 8 bf16 = 4 VGPRs
typedef __attribute__((ext_vector_type(4))) float f32x4;

__device__ inline short f2bf(float v) {
    bf16 t = __float2bfloat16(v);
    return *reinterpret_cast<short*>(&t);
}
__device__ inline unsigned short f2bfu(float v) {
    bf16 t = __float2bfloat16(v);
    return *reinterpret_cast<unsigned short*>(&t);
}

// ---------------- degree histogram (int) ----------------
__global__ void k_deg(const int* __restrict__ dst, int* __restrict__ deg) {
    int stride = gridDim.x * blockDim.x;
    for (int e = blockIdx.x * blockDim.x + threadIdx.x; e < N_EDGES; e += stride)
        atomicAdd(&deg[dst[e]], 1);
}

// ---------------- hierarchical scan: deg -> exclusive prefix (rowcur) ----------------
// scan1: per-chunk sums (wave-shuffle reduce)
__global__ void k_scan1(const int* __restrict__ deg, int* __restrict__ bsum) {
    const int i = blockIdx.x * SB + threadIdx.x;
    int v = (i < N_NODES) ? deg[i] : 0;
#pragma unroll
    for (int off = 32; off > 0; off >>= 1) v += __shfl_down(v, off);
    __shared__ int wsum[SB / 64];
    if ((threadIdx.x & 63) == 0) wsum[threadIdx.x >> 6] = v;
    __syncthreads();
    if (threadIdx.x == 0) {
        int s = 0;
#pragma unroll
        for (int w = 0; w < SB / 64; w++) s += wsum[w];
        bsum[blockIdx.x] = s;
    }
}

// scan2: exclusive scan of the chunk sums (single small block)
__global__ void k_scan2(const int* __restrict__ bsum, int* __restrict__ boff) {
    __shared__ int s[SB];
    const int t = threadIdx.x;
    int v = (t < NCH) ? bsum[t] : 0;
    s[t] = v;
    __syncthreads();
    for (int off = 1; off < SB; off <<= 1) {
        int u = (t >= off) ? s[t - off] : 0;
        __syncthreads();
        s[t] += u;
        __syncthreads();
    }
    if (t < NCH) boff[t] = s[t] - v;   // exclusive
}

// scan3: within-chunk scan + chunk offset
__global__ void k_scan3(const int* __restrict__ deg, const int* __restrict__ boff,
                        int* __restrict__ rowcur) {
    __shared__ int s[SB];
    const int b = blockIdx.x, t = threadIdx.x;
    const int i = b * SB + t;
    int v = (i < N_NODES) ? deg[i] : 0;
    s[t] = v;
    __syncthreads();
    for (int off = 1; off < SB; off <<= 1) {
        int u = (t >= off) ? s[t - off] : 0;
        __syncthreads();
        s[t] += u;
        __syncthreads();
    }
    if (i < N_NODES) rowcur[i] = boff[b] + s[t] - v;   // exclusive
}

// ---------------- deg(int) -> 1/max(deg,1) (float, in place) ----------------
__global__ void k_invdeg(int* degbuf) {
    int i = blockIdx.x * blockDim.x + threadIdx.x;
    if (i < N_NODES) {
        int d = degbuf[i];
        float inv = 1.0f / (float)max(d, 1);
        ((float*)degbuf)[i] = inv;
    }
}

// ---------------- CSR fill ----------------
__global__ void k_fill(const int* __restrict__ src, const int* __restrict__ dst,
                       int* __restrict__ rowcur, int* __restrict__ csr_src) {
    int stride = gridDim.x * blockDim.x;
    for (int e = blockIdx.x * blockDim.x + threadIdx.x; e < N_EDGES; e += stride) {
        int d = dst[e];
        int pos = atomicAdd(&rowcur[d], 1);
        csr_src[pos] = src[e];
    }
}

// ---------------- Wl/Wr -> W^T bf16 ----------------
__global__ void k_wconv(const float* __restrict__ Wl, const float* __restrict__ Wr,
                        bf16* __restrict__ WlT, bf16* __restrict__ WrT) {
    int idx = blockIdx.x * 256 + threadIdx.x;
    if (idx >= NLAYERS * HID * HID) return;
    int l = idx / (HID * HID);
    int rem = idx - l * HID * HID;
    int k = rem >> 7;
    int f = rem & 127;
    size_t o = (size_t)l * HID * HID + (size_t)f * HID + k;
    WlT[o] = __float2bfloat16(Wl[idx]);
    WrT[o] = __float2bfloat16(Wr[idx]);
}

// ---------------- emb_W[300][128] -> embT[128][KPAD] bf16 (zero-padded K) ----------------
__global__ void k_wembT(const float* __restrict__ W, bf16* __restrict__ embT) {
    int idx = blockIdx.x * 256 + threadIdx.x;
    if (idx >= HID * KPAD) return;
    int f = idx / KPAD, k = idx - f * KPAD;
    float v = (k < IN_DIM) ? W[(size_t)k * HID + f] : 0.0f;
    embT[idx] = __float2bfloat16(v);
}

// ---------------- embedding via MFMA: h = relu(x @ W + b), bf16 out ----------------
__global__ void k_embed_mfma(const float* __restrict__ x, const bf16* __restrict__ embT,
                             const float* __restrict__ b, bf16* __restrict__ h) {
    const int wid  = threadIdx.x >> 6;
    const int lane = threadIdx.x & 63;
    const int r0   = blockIdx.x * 64 + wid * 16;
    const int lrow = lane & 15;
    const int kgrp = lane >> 4;

    const int arow = min(r0 + lrow, N_NODES - 1);
    const float* xrow = x + (size_t)arow * IN_DIM;

    f32x4 acc[8];
#pragma unroll
    for (int c = 0; c < 8; c++) acc[c] = (f32x4){0.f, 0.f, 0.f, 0.f};

    for (int kk = 0; kk < KPAD / 32; kk++) {
        const int k0 = kk * 32 + kgrp * 8;
        short8 a;
        if (kk < 9) {
            float4 f0 = *reinterpret_cast<const float4*>(xrow + k0);
            float4 f1 = *reinterpret_cast<const float4*>(xrow + k0 + 4);
            a[0] = f2bf(f0.x); a[1] = f2bf(f0.y); a[2] = f2bf(f0.z); a[3] = f2bf(f0.w);
            a[4] = f2bf(f1.x); a[5] = f2bf(f1.y); a[6] = f2bf(f1.z); a[7] = f2bf(f1.w);
        } else {
#pragma unroll
            for (int j = 0; j < 8; j++) {
                int k = k0 + j;
                a[j] = f2bf((k < IN_DIM) ? xrow[k] : 0.0f);
            }
        }
#pragma unroll
        for (int c = 0; c < 8; c++) {
            short8 bfrag = *reinterpret_cast<const short8*>(embT + (size_t)(c * 16 + lrow) * KPAD + k0);
            acc[c] = __builtin_amdgcn_mfma_f32_16x16x32_bf16(a, bfrag, acc[c], 0, 0, 0);
        }
    }

#pragma unroll
    for (int c = 0; c < 8; c++) {
        const int col = c * 16 + lrow;
        const float bias = b[col];
#pragma unroll
        for (int r = 0; r < 4; r++) {
            const int row = r0 + kgrp * 4 + r;
            if (row < N_NODES)
                h[(size_t)row * HID + col] = __float2bfloat16(fmaxf(acc[c][r] + bias, 0.0f));
        }
    }
}

// ---------------- gather-aggregate: half-wave per edge stream, 8B/lane ----------------
// lanes 0-31 process edges beg, beg+2, ...; lanes 32-63 process beg+1, beg+3, ...
// lane covers features fl*4 .. fl*4+3 (8 B). Cross-half shfl_xor reduce at the end.
__global__ void k_gather(const int* __restrict__ rowend, const int* __restrict__ csr_src,
                         const bf16* __restrict__ h, const float* __restrict__ invdeg,
                         bf16* __restrict__ agg) {
    const int node = blockIdx.x * (blockDim.x >> 6) + (threadIdx.x >> 6);
    if (node >= N_NODES) return;
    const int lane = threadIdx.x & 63;
    const int half = lane >> 5;
    const int fl   = lane & 31;
    const int beg = (node == 0) ? 0 : rowend[node - 1];
    const int end = rowend[node];

    float a0 = 0.f, a1 = 0.f, a2 = 0.f, a3 = 0.f;
    float b0 = 0.f, b1 = 0.f, b2 = 0.f, b3 = 0.f;

    int e = beg + half;
    for (; e + 4 <= end; e += 4) {      // e and e+2 both valid
        int s0 = csr_src[e];
        int s1 = csr_src[e + 2];
        uint2 v0 = *reinterpret_cast<const uint2*>(h + (size_t)s0 * HID + fl * 4);
        uint2 v1 = *reinterpret_cast<const uint2*>(h + (size_t)s1 * HID + fl * 4);
        a0 += __uint_as_float((v0.x & 0xffffu) << 16); a1 += __uint_as_float(v0.x & 0xffff0000u);
        a2 += __uint_as_float((v0.y & 0xffffu) << 16); a3 += __uint_as_float(v0.y & 0xffff0000u);
        b0 += __uint_as_float((v1.x & 0xffffu) << 16); b1 += __uint_as_float(v1.x & 0xffff0000u);
        b2 += __uint_as_float((v1.y & 0xffffu) << 16); b3 += __uint_as_float(v1.y & 0xffff0000u);
    }
    for (; e < end; e += 2) {
        int s = csr_src[e];
        uint2 v = *reinterpret_cast<const uint2*>(h + (size_t)s * HID + fl * 4);
        a0 += __uint_as_float((v.x & 0xffffu) << 16); a1 += __uint_as_float(v.x & 0xffff0000u);
        a2 += __uint_as_float((v.y & 0xffffu) << 16); a3 += __uint_as_float(v.y & 0xffff0000u);
    }
    a0 += b0; a1 += b1; a2 += b2; a3 += b3;

    // cross-half reduce
    a0 += __shfl_xor(a0, 32);
    a1 += __shfl_xor(a1, 32);
    a2 += __shfl_xor(a2, 32);
    a3 += __shfl_xor(a3, 32);

    if (half == 0) {
        const float id = invdeg[node];
        uint2 o;
        o.x = (unsigned)f2bfu(a0 * id) | ((unsigned)f2bfu(a1 * id) << 16);
        o.y = (unsigned)f2bfu(a2 * id) | ((unsigned)f2bfu(a3 * id) << 16);
        *reinterpret_cast<uint2*>(agg + (size_t)node * HID + fl * 4) = o;
    }
}

// ---------------- combine via MFMA: out = relu(agg @ Wl + bl + h_in @ Wr) ----------------
template<int STORE_F32>
__global__ void k_combine_mfma(const bf16* __restrict__ agg, const bf16* __restrict__ h_in,
                               const bf16* __restrict__ WlT, const bf16* __restrict__ WrT,
                               const float* __restrict__ bl, void* __restrict__ outp) {
    const int wid  = threadIdx.x >> 6;
    const int lane = threadIdx.x & 63;
    const int r0   = blockIdx.x * 64 + wid * 16;
    const int lrow = lane & 15;
    const int kgrp = lane >> 4;

    f32x4 acc[8];
#pragma unroll
    for (int c = 0; c < 8; c++) acc[c] = (f32x4){0.f, 0.f, 0.f, 0.f};

    const int arow = min(r0 + lrow, N_NODES - 1);

#pragma unroll
    for (int m = 0; m < 2; m++) {
        const bf16* A  = m ? h_in : agg;
        const bf16* BT = m ? WrT  : WlT;
#pragma unroll
        for (int kk = 0; kk < 4; kk++) {
            const int k0 = kk * 32 + kgrp * 8;
            short8 a = *reinterpret_cast<const short8*>(A + (size_t)arow * HID + k0);
#pragma unroll
            for (int c = 0; c < 8; c++) {
                short8 b = *reinterpret_cast<const short8*>(BT + (size_t)(c * 16 + lrow) * HID + k0);
                acc[c] = __builtin_amdgcn_mfma_f32_16x16x32_bf16(a, b, acc[c], 0, 0, 0);
            }
        }
    }

#pragma unroll
    for (int c = 0; c < 8; c++) {
        const int col = c * 16 + lrow;
        const float bias = bl[col];
#pragma unroll
        for (int r = 0; r < 4; r++) {
            const int row = r0 + kgrp * 4 + r;
            if (row < N_NODES) {
                float v = fmaxf(acc[c][r] + bias, 0.0f);
                if (STORE_F32)
                    ((float*)outp)[(size_t)row * HID + col] = v;
                else
                    ((bf16*)outp)[(size_t)row * HID + col] = __float2bfloat16(v);
            }
        }
    }
}

extern "C" void kernel_launch(void* const* d_in, const int* in_sizes, int n_in,
                              void* d_out, int out_size, void* d_ws, size_t ws_size,
                              hipStream_t stream) {
    const float* x     = (const float*)d_in[0];
    const int*   ei    = (const int*)d_in[1];
    const float* emb_W = (const float*)d_in[2];
    const float* emb_b = (const float*)d_in[3];
    const float* Wl    = (const float*)d_in[4];
    const float* bl    = (const float*)d_in[5];
    const float* Wr    = (const float*)d_in[6];

    const int* src = ei;
    const int* dst = ei + N_EDGES;

    // workspace layout
    char* ws = (char*)d_ws;
    size_t o = 0;
    int*  degbuf = (int*)(ws + o);  o += ((size_t)N_NODES * 4 + 255) & ~(size_t)255;
    int*  rowcur = (int*)(ws + o);  o += ((size_t)N_NODES * 4 + 255) & ~(size_t)255;
    int*  csrsrc = (int*)(ws + o);  o += ((size_t)N_EDGES * 4 + 255) & ~(size_t)255;
    int*  bsum   = (int*)(ws + o);  o += ((size_t)NCH * 4 + 255) & ~(size_t)255;
    int*  boff   = (int*)(ws + o);  o += ((size_t)NCH * 4 + 255) & ~(size_t)255;
    bf16* WlT    = (bf16*)(ws + o); o += ((size_t)NLAYERS * HID * HID * 2 + 255) & ~(size_t)255;
    bf16* WrT    = (bf16*)(ws + o); o += ((size_t)NLAYERS * HID * HID * 2 + 255) & ~(size_t)255;
    bf16* embT   = (bf16*)(ws + o); o += ((size_t)HID * KPAD * 2 + 255) & ~(size_t)255;
    bf16* bufA   = (bf16*)(ws + o); o += ((size_t)N_NODES * HID * 2 + 255) & ~(size_t)255;
    bf16* bufB   = (bf16*)(ws + o);

    // ---- build CSR ----
    hipMemsetAsync(degbuf, 0, (size_t)N_NODES * sizeof(int), stream);
    k_deg<<<1024, 256, 0, stream>>>(dst, degbuf);
    k_scan1<<<NCH, SB, 0, stream>>>(degbuf, bsum);
    k_scan2<<<1, SB, 0, stream>>>(bsum, boff);
    k_scan3<<<NCH, SB, 0, stream>>>(degbuf, boff, rowcur);
    k_invdeg<<<(N_NODES + 255) / 256, 256, 0, stream>>>(degbuf);
    const float* invdeg = (const float*)degbuf;
    k_fill<<<1024, 256, 0, stream>>>(src, dst, rowcur, csrsrc);
    // rowcur[n] is now the END offset of row n

    // ---- weight prep ----
    k_wconv<<<(NLAYERS * HID * HID + 255) / 256, 256, 0, stream>>>(Wl, Wr, WlT, WrT);
    k_wembT<<<(HID * KPAD + 255) / 256, 256, 0, stream>>>(emb_W, embT);

    // ---- h0 = relu(x @ emb_W + emb_b) -> bufA (bf16), via MFMA ----
    const int cgrid = (N_NODES + 63) / 64;   // 782
    k_embed_mfma<<<cgrid, 256, 0, stream>>>(x, embT, emb_b, bufA);

    for (int l = 0; l < NLAYERS; l++) {
        bf16* h_in = (l & 1) ? bufB : bufA;
        bf16* aggb = (l & 1) ? bufA : bufB;
        k_gather<<<(N_NODES + 3) / 4, 256, 0, stream>>>(rowcur, csrsrc, h_in, invdeg, aggb);
        const bf16* wlt = WlT + (size_t)l * HID * HID;
        const bf16* wrt = WrT + (size_t)l * HID * HID;
        const float* blp = bl + (size_t)l * HID;
        if (l == NLAYERS - 1)
            k_combine_mfma<1><<<cgrid, 256, 0, stream>>>(aggb, h_in, wlt, wrt, blp, d_out);
        else
            k_combine_mfma<0><<<cgrid, 256, 0, stream>>>(aggb, h_in, wlt, wrt, blp, aggb);
    }
}